// Round 7
// baseline (197.564 us; speedup 1.0000x reference)
//
#include <hip/hip_runtime.h>
#include <math.h>

#define T_LEN 512
#define B_N   1024
#define K_N   48
#define START_TAG (K_N - 2)
#define STOP_TAG  (K_N - 1)
#define NEG   -10000.0f

// Forward/backward split CRF + LPT at 1 wave/SIMD, de-serialized step engine.
//
// R6 accounting: pace 684 cy/step; issue (from VALUBusy back-solve) ~344
// cy/step, dominated by 46 v_readlane @ ~6cy. This round strips every
// NON-broadcast op off the serial chain:
//  * exp(feat) moved to PREFETCH time (8-16 steps early) — the transcendental
//    and its latency leave the chain.
//  * per-step folded renorm replaces the every-4-step serial renorm:
//    g = readlane(q,0) issues at chain start; rcp(g)/log2(g) run in matvec
//    slack; rcp(g) folds into the EXISTING scale multiply; C2 += log2(g) is
//    an independent chain (native v_log_f32; x ln2 once at the end).
//    q'_0 = w_0/g stays O(per-step growth) -> no overflow, ever.
//  * tail skips its second 8-step half when rem <= 8.
//
// Carried, load-bearing (R0-R6):
//  * readlane broadcast + v_pk_fma_f32 engine (best of 4 broadcast mechanisms
//    tried: readlane 684 < LDS rt 820 < dpp systolic 871 < barrier 1109).
//  * 46 k-terms; step 0 peeled in closed form (k=46 START only feeds t=0,
//    k=47 STOP column is exp(-1e4)=0).
//  * LPT counting sort, longest-first dispatch; fwd/bwd pair balanced +-1.
//  * waves_per_eu(1,1): solo wave per SIMD (W=2 raises per-wave pace 1.6x).
//  * unconditional clamped loads, 8-ahead static ping-pong; no barrier/LDS/
//    dpp on the recursion chain; unmasked bulk blocks + masked tail.

using f32x2 = __attribute__((ext_vector_type(2))) float;

__device__ __forceinline__ float bcast(float v, int k) {
    return __uint_as_float(__builtin_amdgcn_readlane(__float_as_uint(v), k));
}

// w_lane = sum_{k<46} E[lane,k] * (lane k of src).
// 46 readlane + 23 v_pk_fma_f32 over 4 accumulator chains.
__device__ __forceinline__ float matvec46(const f32x2 (&E2)[23], float src) {
    const int qb = __float_as_int(src);
    f32x2 a0 = {0.f, 0.f}, a1 = {0.f, 0.f}, a2 = {0.f, 0.f}, a3 = {0.f, 0.f};
#define PKFMA(P, ACC) { \
        const unsigned int lo = (unsigned int)__builtin_amdgcn_readlane(qb, 2*(P)); \
        const unsigned int hi = (unsigned int)__builtin_amdgcn_readlane(qb, 2*(P)+1); \
        const unsigned long long sp = ((unsigned long long)hi << 32) | lo; \
        asm("v_pk_fma_f32 %0, %1, %2, %0" : "+v"(ACC) : "v"(E2[P]), "s"(sp)); }
    PKFMA(0,a0)  PKFMA(1,a1)  PKFMA(2,a2)  PKFMA(3,a3)
    PKFMA(4,a0)  PKFMA(5,a1)  PKFMA(6,a2)  PKFMA(7,a3)
    PKFMA(8,a0)  PKFMA(9,a1)  PKFMA(10,a2) PKFMA(11,a3)
    PKFMA(12,a0) PKFMA(13,a1) PKFMA(14,a2) PKFMA(15,a3)
    PKFMA(16,a0) PKFMA(17,a1) PKFMA(18,a2) PKFMA(19,a3)
    PKFMA(20,a0) PKFMA(21,a1) PKFMA(22,a2)
#undef PKFMA
    const f32x2 s = (a0 + a1) + (a2 + a3);
    return s.x + s.y;
}

// Full renorm (final use only): q /= q_0, C += log(q_0).
__device__ __forceinline__ void renorm(float& q, float& C) {
    const float g = bcast(q, 0);
    C += __logf(g);
    q *= __builtin_amdgcn_rcpf(g);
}

// Run `steps` recursion steps. f-arrays hold PRE-EXPONENTIATED feats.
// BWD=0: q' = (ef .* (E q)) * rcp(g).  BWD=1: q' = E^T ((ef*rcp(g)) .* q).
// g = q_0 (pre-step): per-step folded renorm, C2 accumulates log2(g).
template <int BWD>
__device__ __forceinline__ void run_chain(const float* __restrict__ fb,
                                          int rbase,
                                          const f32x2 (&E2)[23],
                                          int steps, int lane_c,
                                          float& q, float& C2)
{
    const size_t sT = (size_t)B_N * K_N;
    auto row_of = [&](int i) -> int {
        int r = BWD ? (rbase - i) : (rbase + i);
        r = (r < 0) ? 0 : r;
        r = (r > T_LEN - 1) ? (T_LEN - 1) : r;   // physically valid; junk rows
        return r;                                 // only feed frozen steps
    };
    auto step = [&](bool on, float ef) {
        const float g = bcast(q, 0);              // issues right after q born
        const float r = __builtin_amdgcn_rcpf(g); // hides in matvec slack
        if (BWD) {
            const float u = q * (ef * r);         // ef*r off-chain; 1 mul on
            const float w = matvec46(E2, u);
            q = on ? w : q;
        } else {
            const float w = matvec46(E2, q);
            q = on ? w * (ef * r) : q;            // same single scale multiply
        }
        C2 += on ? __builtin_amdgcn_logf(g) : 0.0f;  // native log2, own chain
    };

    float f0[8], f1[8];
    #pragma unroll
    for (int i = 0; i < 8; ++i)
        f0[i] = __expf(fb[(size_t)row_of(i) * sT + lane_c]);

    const int nfull = steps >> 4;                 // unmasked 16-step blocks
    #pragma unroll 1
    for (int blk = 0; blk < nfull; ++blk) {
        const int t0 = blk * 16;
        #pragma unroll
        for (int i = 0; i < 8; ++i)
            f1[i] = __expf(fb[(size_t)row_of(t0 + 8 + i) * sT + lane_c]);
        #pragma unroll
        for (int i = 0; i < 8; ++i)
            step(true, f0[i]);                    // cndmask folds away
        #pragma unroll
        for (int i = 0; i < 8; ++i)
            f0[i] = __expf(fb[(size_t)row_of(t0 + 16 + i) * sT + lane_c]);
        #pragma unroll
        for (int i = 0; i < 8; ++i)
            step(true, f1[i]);
    }
    const int rem = steps & 15;                   // masked tail, <= 16 steps
    if (rem) {
        const int t0 = nfull * 16;
        #pragma unroll
        for (int i = 0; i < 8; ++i)
            f1[i] = __expf(fb[(size_t)row_of(t0 + 8 + i) * sT + lane_c]);
        #pragma unroll
        for (int i = 0; i < 8; ++i)
            step(i < rem, f0[i]);
        if (rem > 8) {
            #pragma unroll
            for (int i = 0; i < 8; ++i)
                step(8 + i < rem, f1[i]);
        }
    }
}

// ---- LPT sort: perm = batch ids by DESCENDING length (counting sort). ----
__global__ __launch_bounds__(1024)
void lpt_sort_kernel(const int* __restrict__ lengths, int* __restrict__ perm)
{
    __shared__ int hist[512];
    __shared__ int offs[512];
    const int tid = threadIdx.x;
    if (tid < 512) hist[tid] = 0;
    __syncthreads();
    const int len = lengths[tid];          // len in [1, 512]
    const int key = 512 - len;             // [0, 511], 0 = longest
    atomicAdd(&hist[key], 1);
    __syncthreads();
    if (tid < 512) offs[tid] = hist[tid];
    __syncthreads();
    for (int d = 1; d < 512; d <<= 1) {    // inclusive Hillis-Steele scan
        int v = 0;
        if (tid < 512 && tid >= d) v = offs[tid - d];
        __syncthreads();
        if (tid < 512) offs[tid] += v;
        __syncthreads();
    }
    const int p = atomicSub(&offs[key], 1) - 1;
    perm[p] = tid;
}

__global__ __launch_bounds__(128)
__attribute__((amdgpu_waves_per_eu(1, 1)))
void crf_fused_kernel(
    const float* __restrict__ feats,    // (T, B, K)
    const float* __restrict__ trans,    // (K, K)
    const int*   __restrict__ tags,     // (B, T)
    const int*   __restrict__ lengths,  // (B,)
    const int*   __restrict__ perm,     // (B,) LPT order
    float* __restrict__ out)
{
    const int b      = perm[blockIdx.x];          // LPT: longest first
    const int tid    = threadIdx.x;
    const int lane   = tid & 63;
    const int wid    = tid >> 6;                  // 0 = forward, 1 = backward
    const int len    = lengths[b];
    const int lm1    = len - 1;
    const int m      = (len + 1) >> 1;            // split point
    const int lane_c = (lane < K_N) ? lane : (K_N - 1);

    __shared__ __attribute__((aligned(16))) float sh_p[64];
    __shared__ float sh_cb;
    __shared__ float sh_gold;

    const float* fb = feats + (size_t)b * K_N;
    const size_t sT = (size_t)B_N * K_N;

    // Coefficient pairs for k = 0..45 (46,47 contribute 0 after the peel).
    // fwd: row lane of E = exp(trans); bwd: row lane of E^T.
    f32x2 E2[23];
    if (wid == 0) {
        const float* tr = trans + lane_c * K_N;
        #pragma unroll
        for (int p = 0; p < 23; ++p) {
            E2[p].x = __expf(tr[2 * p]);
            E2[p].y = __expf(tr[2 * p + 1]);
        }
    } else {
        #pragma unroll
        for (int p = 0; p < 23; ++p) {
            E2[p].x = __expf(trans[(2 * p) * K_N + lane_c]);
            E2[p].y = __expf(trans[(2 * p + 1) * K_N + lane_c]);
        }
    }

    float q, C2 = 0.0f, C = 0.0f;
    if (wid == 0) {
        // Peeled step 0: q_j = exp(trans[j,START] + feat0_j). Lane 46 -> 0.
        q = __expf(trans[lane_c * K_N + START_TAG] + fb[lane_c]);
        run_chain<0>(fb, 1, E2, m - 1, lane_c, q, C2);
    } else {
        q = __expf(trans[STOP_TAG * K_N + lane_c]);   // beta_len
        run_chain<1>(fb, lm1, E2, len - m, lane_c, q, C2);
    }
    C = C2 * 0.6931471805599453f;   // log2 -> ln
    renorm(q, C);                   // bound q for the combine dot (q_0 = 1)

    if (wid == 1) {
        // Gold path score, striped over t.
        float gsum = 0.0f;
        for (int t = lane; t < len; t += 64) {
            int next = tags[(size_t)b * T_LEN + t];
            int prev = (t == 0) ? START_TAG : tags[(size_t)b * T_LEN + t - 1];
            gsum += trans[next * K_N + prev] + fb[(size_t)t * sT + next];
        }
        #pragma unroll
        for (int off = 32; off >= 1; off >>= 1)
            gsum += __shfl_xor(gsum, off);

        sh_p[lane] = q;
        if (lane == 0) {
            sh_cb = C;
            int last = tags[(size_t)b * T_LEN + len - 1];
            sh_gold = gsum + trans[STOP_TAG * K_N + last];
        }
    }
    __syncthreads();

    if (wid == 0) {
        // log_z = C_f + C_b + log( sum_j q_j p_j ); j=46,47 terms are 0 by
        // construction (q_46 = 0, p_47 = 0), pads excluded by lane < K_N.
        float term = (lane < K_N) ? q * sh_p[lane] : 0.0f;
        #pragma unroll
        for (int off = 32; off >= 1; off >>= 1)
            term += __shfl_xor(term, off);
        if (lane == 0) {
            float log_z = C + sh_cb + __logf(term);
            atomicAdd(out, log_z - sh_gold);
        }
    }
}

extern "C" void kernel_launch(void* const* d_in, const int* in_sizes, int n_in,
                              void* d_out, int out_size, void* d_ws, size_t ws_size,
                              hipStream_t stream) {
    const float* feats   = (const float*)d_in[0];
    const float* trans   = (const float*)d_in[1];
    const int*   tags    = (const int*)d_in[2];
    const int*   lengths = (const int*)d_in[3];
    float* out = (float*)d_out;
    int*   perm = (int*)d_ws;                    // 4 KB of workspace

    hipMemsetAsync(out, 0, sizeof(float) * out_size, stream);
    lpt_sort_kernel<<<1, B_N, 0, stream>>>(lengths, perm);
    crf_fused_kernel<<<B_N, 128, 0, stream>>>(feats, trans, tags, lengths, perm, out);
}

// Round 8
// 187.739 us; speedup vs baseline: 1.0523x; 1.0523x over previous
//
#include <hip/hip_runtime.h>
#include <math.h>

#define T_LEN 512
#define B_N   1024
#define K_N   48
#define START_TAG (K_N - 2)
#define STOP_TAG  (K_N - 1)
#define NEG   -10000.0f

// Forward/backward split CRF + LPT at 1 wave/SIMD, ds_bpermute broadcast.
//
// R5-R7 accounting: pace stuck at ~690 cy/step because the 46 per-step
// broadcasts ride the VALU pipe as v_readlane (~6cy each, SGPR hazards) and
// serialize against the FMAs. This round swaps the MECHANISM, nothing else:
//   ds_bpermute_b32 = LDS crossbar WITHOUT storage (no write+drain round
//   trip — that was R2's 820cy/step failure), uniform addr 4k = broadcast of
//   lane k (conflict-free), result in a VGPR (no SGPR hazards), issues on
//   the DS pipe -> co-issues with the VALU fma stream. In-order returns with
//   counted lgkmcnt (compiler-inserted; lgkmcnt cap 15 still covers the
//   ~40cy crossbar latency at ~5.8cy/op issue).
// Mechanism ladder so far (cy/step): readlane 689 < LDS rt 820 < dpp 871 <
// barrier 1109; bpermute predicted ~330-400.
//
// Carried, load-bearing (R0-R7):
//  * R6 step semantics EXACTLY (R7's per-step folded renorm was -8%: +1
//    readlane +1 rcp +1 log2 per step; exp(feat) hoisting is already done by
//    the compiler since fv has no q dependence).
//  * 46 k-terms; step 0 peeled closed-form (k=46 START only feeds t=0;
//    k=47 STOP col = exp(-1e4) = 0).
//  * renorm every 4 steps (representation-only, safe while frozen).
//  * LPT counting sort, longest-first; fwd/bwd pair balanced to +-1 step.
//  * waves_per_eu(1,1): solo wave/SIMD (W=2 raised per-wave pace 1.7x, R4).
//  * unconditional clamped loads, 8-ahead static ping-pong; unmasked bulk
//    blocks + one masked tail; no barrier on the recursion chain.

__device__ __forceinline__ float bcast(float v, int k) {
    return __uint_as_float(__builtin_amdgcn_readlane(__float_as_uint(v), k));
}

// w_lane = sum_{k<46} E[lane,k] * (lane k of src).
// 46 ds_bpermute (DS pipe) + 46 fma (VALU pipe), 4 accumulator chains.
__device__ __forceinline__ float matvec46(const float (&E)[46], float src) {
    const int qb = __float_as_int(src);
    float a0 = 0.f, a1 = 0.f, a2 = 0.f, a3 = 0.f;
    #pragma unroll
    for (int k = 0; k + 4 <= 46; k += 4) {
        const float s0 = __int_as_float(__builtin_amdgcn_ds_bpermute(4 * (k + 0), qb));
        const float s1 = __int_as_float(__builtin_amdgcn_ds_bpermute(4 * (k + 1), qb));
        const float s2 = __int_as_float(__builtin_amdgcn_ds_bpermute(4 * (k + 2), qb));
        const float s3 = __int_as_float(__builtin_amdgcn_ds_bpermute(4 * (k + 3), qb));
        a0 = fmaf(E[k + 0], s0, a0);
        a1 = fmaf(E[k + 1], s1, a1);
        a2 = fmaf(E[k + 2], s2, a2);
        a3 = fmaf(E[k + 3], s3, a3);
    }
    {   // k = 44, 45
        const float s0 = __int_as_float(__builtin_amdgcn_ds_bpermute(4 * 44, qb));
        const float s1 = __int_as_float(__builtin_amdgcn_ds_bpermute(4 * 45, qb));
        a0 = fmaf(E[44], s0, a0);
        a1 = fmaf(E[45], s1, a1);
    }
    return (a0 + a1) + (a2 + a3);
}

// Representation change only: q /= q_0, C += log(q_0). Safe while frozen.
__device__ __forceinline__ void renorm(float& q, float& C) {
    const float g = bcast(q, 0);
    C += __logf(g);
    q *= __builtin_amdgcn_rcpf(g);
}

// Run `steps` recursion steps. BWD=0: q' = exp(f) * (E q), rows rbase,+1,...
// BWD=1: q' = E^T (exp(f) .* q), rows rbase,-1,...
template <int BWD>
__device__ __forceinline__ void run_chain(const float* __restrict__ fb,
                                          int rbase,
                                          const float (&E)[46],
                                          int steps, int lane_c,
                                          float& q, float& C)
{
    const size_t sT = (size_t)B_N * K_N;
    auto row_of = [&](int i) -> int {
        int r = BWD ? (rbase - i) : (rbase + i);
        r = (r < 0) ? 0 : r;
        r = (r > T_LEN - 1) ? (T_LEN - 1) : r;   // physically valid; junk rows
        return r;                                 // only feed frozen steps
    };
    auto step = [&](bool on, float fv) {
        if (BWD) {
            const float u = q * __expf(fv);       // feat BEFORE matvec
            const float w = matvec46(E, u);
            q = on ? w : q;
        } else {
            const float w = matvec46(E, q);
            q = on ? w * __expf(fv) : q;          // feat AFTER matvec
        }
    };

    float f0[8], f1[8];
    #pragma unroll
    for (int i = 0; i < 8; ++i)
        f0[i] = fb[(size_t)row_of(i) * sT + lane_c];

    const int nfull = steps >> 4;                 // unmasked 16-step blocks
    #pragma unroll 1
    for (int blk = 0; blk < nfull; ++blk) {
        const int t0 = blk * 16;
        #pragma unroll
        for (int i = 0; i < 8; ++i)
            f1[i] = fb[(size_t)row_of(t0 + 8 + i) * sT + lane_c];
        #pragma unroll
        for (int i = 0; i < 8; ++i) {
            step(true, f0[i]);                    // cndmask folds away
            if (i == 3 || i == 7) renorm(q, C);
        }
        #pragma unroll
        for (int i = 0; i < 8; ++i)
            f0[i] = fb[(size_t)row_of(t0 + 16 + i) * sT + lane_c];
        #pragma unroll
        for (int i = 0; i < 8; ++i) {
            step(true, f1[i]);
            if (i == 3 || i == 7) renorm(q, C);
        }
    }
    const int rem = steps & 15;                   // one masked tail block
    if (rem) {
        const int t0 = nfull * 16;
        #pragma unroll
        for (int i = 0; i < 8; ++i)
            f1[i] = fb[(size_t)row_of(t0 + 8 + i) * sT + lane_c];
        #pragma unroll
        for (int i = 0; i < 8; ++i) {
            step(i < rem, f0[i]);
            if (i == 3 || i == 7) renorm(q, C);
        }
        if (rem > 8) {
            #pragma unroll
            for (int i = 0; i < 8; ++i) {
                step(8 + i < rem, f1[i]);
                if (i == 3 || i == 7) renorm(q, C);
            }
        }
    }
}

// ---- LPT sort: perm = batch ids by DESCENDING length (counting sort). ----
__global__ __launch_bounds__(1024)
void lpt_sort_kernel(const int* __restrict__ lengths, int* __restrict__ perm)
{
    __shared__ int hist[512];
    __shared__ int offs[512];
    const int tid = threadIdx.x;
    if (tid < 512) hist[tid] = 0;
    __syncthreads();
    const int len = lengths[tid];          // len in [1, 512]
    const int key = 512 - len;             // [0, 511], 0 = longest
    atomicAdd(&hist[key], 1);
    __syncthreads();
    if (tid < 512) offs[tid] = hist[tid];
    __syncthreads();
    for (int d = 1; d < 512; d <<= 1) {    // inclusive Hillis-Steele scan
        int v = 0;
        if (tid < 512 && tid >= d) v = offs[tid - d];
        __syncthreads();
        if (tid < 512) offs[tid] += v;
        __syncthreads();
    }
    const int p = atomicSub(&offs[key], 1) - 1;
    perm[p] = tid;
}

__global__ __launch_bounds__(128)
__attribute__((amdgpu_waves_per_eu(1, 1)))
void crf_fused_kernel(
    const float* __restrict__ feats,    // (T, B, K)
    const float* __restrict__ trans,    // (K, K)
    const int*   __restrict__ tags,     // (B, T)
    const int*   __restrict__ lengths,  // (B,)
    const int*   __restrict__ perm,     // (B,) LPT order
    float* __restrict__ out)
{
    const int b      = perm[blockIdx.x];          // LPT: longest first
    const int tid    = threadIdx.x;
    const int lane   = tid & 63;
    const int wid    = tid >> 6;                  // 0 = forward, 1 = backward
    const int len    = lengths[b];
    const int lm1    = len - 1;
    const int m      = (len + 1) >> 1;            // split point
    const int lane_c = (lane < K_N) ? lane : (K_N - 1);

    __shared__ __attribute__((aligned(16))) float sh_p[64];
    __shared__ float sh_cb;
    __shared__ float sh_gold;

    const float* fb = feats + (size_t)b * K_N;
    const size_t sT = (size_t)B_N * K_N;

    // Coefficients k = 0..45 (46,47 contribute 0 after the peel).
    // fwd: row lane of E = exp(trans); bwd: row lane of E^T.
    float E[46];
    if (wid == 0) {
        const float* tr = trans + lane_c * K_N;
        #pragma unroll
        for (int k = 0; k < 46; ++k) E[k] = __expf(tr[k]);
    } else {
        #pragma unroll
        for (int k = 0; k < 46; ++k) E[k] = __expf(trans[k * K_N + lane_c]);
    }

    float q, C = 0.0f;
    if (wid == 0) {
        // Peeled step 0: q_j = exp(trans[j,START] + feat0_j). Lane 46 -> 0.
        q = __expf(trans[lane_c * K_N + START_TAG] + fb[lane_c]);
        run_chain<0>(fb, 1, E, m - 1, lane_c, q, C);
    } else {
        q = __expf(trans[STOP_TAG * K_N + lane_c]);   // beta_len
        run_chain<1>(fb, lm1, E, len - m, lane_c, q, C);
    }
    renorm(q, C);   // bound q for the combine dot (q_0 == 1 after this)

    if (wid == 1) {
        // Gold path score, striped over t.
        float gsum = 0.0f;
        for (int t = lane; t < len; t += 64) {
            int next = tags[(size_t)b * T_LEN + t];
            int prev = (t == 0) ? START_TAG : tags[(size_t)b * T_LEN + t - 1];
            gsum += trans[next * K_N + prev] + fb[(size_t)t * sT + next];
        }
        #pragma unroll
        for (int off = 32; off >= 1; off >>= 1)
            gsum += __shfl_xor(gsum, off);

        sh_p[lane] = q;
        if (lane == 0) {
            sh_cb = C;
            int last = tags[(size_t)b * T_LEN + len - 1];
            sh_gold = gsum + trans[STOP_TAG * K_N + last];
        }
    }
    __syncthreads();

    if (wid == 0) {
        // log_z = C_f + C_b + log( sum_j q_j p_j ); j=46,47 terms are 0 by
        // construction (q_46 = 0, p_47 = 0), pads excluded by lane < K_N.
        float term = (lane < K_N) ? q * sh_p[lane] : 0.0f;
        #pragma unroll
        for (int off = 32; off >= 1; off >>= 1)
            term += __shfl_xor(term, off);
        if (lane == 0) {
            float log_z = C + sh_cb + __logf(term);
            atomicAdd(out, log_z - sh_gold);
        }
    }
}

extern "C" void kernel_launch(void* const* d_in, const int* in_sizes, int n_in,
                              void* d_out, int out_size, void* d_ws, size_t ws_size,
                              hipStream_t stream) {
    const float* feats   = (const float*)d_in[0];
    const float* trans   = (const float*)d_in[1];
    const int*   tags    = (const int*)d_in[2];
    const int*   lengths = (const int*)d_in[3];
    float* out = (float*)d_out;
    int*   perm = (int*)d_ws;                    // 4 KB of workspace

    hipMemsetAsync(out, 0, sizeof(float) * out_size, stream);
    lpt_sort_kernel<<<1, B_N, 0, stream>>>(lengths, perm);
    crf_fused_kernel<<<B_N, 128, 0, stream>>>(feats, trans, tags, lengths, perm, out);
}